// Round 13
// baseline (1248.713 us; speedup 1.0000x reference)
//
#include <hip/hip_runtime.h>
#include <hip/hip_bf16.h>

// Problem constants (PentachoronCrossAttention)
#define Bsz   8192
#define Vn    5
#define Dm    1792
#define Hn    14
#define HDm   128
#define Mrows (Bsz * Vn)   // 40960
#define N1    (3 * Dm)     // 5376
#define Kd    Dm           // 1792

typedef float f32x4  __attribute__((ext_vector_type(4)));
typedef float f32x16 __attribute__((ext_vector_type(16)));
typedef short bf16x8 __attribute__((ext_vector_type(8)));

__device__ __forceinline__ ushort f2bf(float f) {
    unsigned u = __float_as_uint(f);
    u += 0x7fffu + ((u >> 16) & 1u);   // round-to-nearest-even
    return (ushort)(u >> 16);
}
__device__ __forceinline__ float bf2f(ushort h) {
    return __uint_as_float(((unsigned)h) << 16);
}

#define AS1(p) ((const __attribute__((address_space(1))) void*)(p))
#define AS3(p) ((__attribute__((address_space(3))) void*)(p))

// ---------------- fused f32 -> bf16 convert (3 regions, one launch) ----------------
__global__ void cvt3_kernel(const float* __restrict__ in0, ushort* __restrict__ out0, int n0,
                            const float* __restrict__ in1, ushort* __restrict__ out1, int n1,
                            const float* __restrict__ in2, ushort* __restrict__ out2, int n2) {
    int i = blockIdx.x * blockDim.x + threadIdx.x;
    int stride = gridDim.x * blockDim.x;
    int ntot = n0 + n1 + n2;
    for (int idx = i; idx < ntot; idx += stride) {
        const float* src; ushort* dst; int k;
        if (idx < n0)            { src = in0; dst = out0; k = idx; }
        else if (idx < n0 + n1)  { src = in1; dst = out1; k = idx - n0; }
        else                     { src = in2; dst = out2; k = idx - n0 - n1; }
        float4 v = reinterpret_cast<const float4*>(src)[k];
        ushort4 o;
        o.x = f2bf(v.x); o.y = f2bf(v.y); o.z = f2bf(v.z); o.w = f2bf(v.w);
        reinterpret_cast<ushort4*>(dst)[k] = o;
    }
}

// ---------------- 256x256 8-phase bf16 GEMM, C = A * Bw^T + bias ----------------
// Schedule FROZEN at round-11 (2-phase windows, VMC(4) ledger, grouped raster).
// Round-13: MFMA 16x16x32 -> 32x32x16 (ubench 2382 vs 2075 TF, half the insts).
// Frag: row/col = lane&31, k = (lane>>5)*8 + j -> per-lane 16B at
//   log_slot = (lane>>5) + kb/8 (kb in {0,16} within the 32-k unit).
// Swizzle unchanged: phys_slot = log ^ ((row>>1)&3); bank-group (4row+phys)%8
//   covers all 8 groups per 8 consecutive rows -> conflict-free (canary: PMC).
// C/D (m74/m101): col = lane&31, row = (reg&3)+8*(reg>>2)+4*(lane>>5).
template<bool OUT_BF16>
__global__ __launch_bounds__(512, 2) void gemm8p(
    const ushort* __restrict__ A,
    const ushort* __restrict__ Bw,
    const float* __restrict__ bias,
    void* __restrict__ Cout,
    int M, int N, int K)
{
    __shared__ __align__(16) char smem[131072];

    const int nTN = N >> 8;
    int bid = blockIdx.x;
    int cpx = gridDim.x >> 3;                 // grid % 8 == 0 for both launches
    int swz = (bid & 7) * cpx + (bid >> 3);   // XCD-bijective chunk swizzle
    int gsz = 4 * nTN;
    int g = swz / gsz, r = swz - g * gsz;
    int bm = g * 4 + (r & 3);
    int bn = r >> 2;

    int t = threadIdx.x;
    int lane = t & 63, w = t >> 6;
    int wrow = (w >> 2) * 128;                // 2 waves in M
    int wcol = (w & 3) * 64;                  // 4 waves in N
    int l5 = lane & 31, hi = lane >> 5;
    int xsw = (l5 >> 1) & 3;                  // swizzle operand (row bits 1-2)
    // per-kb lane-constant offsets (row*64 + swizzled 16B slot)
    int aOffK0 = (wrow + l5) * 64 + ((hi ^ xsw) << 4);
    int aOffK1 = (wrow + l5) * 64 + (((hi | 2) ^ xsw) << 4);
    int bOffK0 = 32768 + (wcol + l5) * 64 + ((hi ^ xsw) << 4);
    int bOffK1 = 32768 + (wcol + l5) * 64 + (((hi | 2) ^ xsw) << 4);

    size_t K2 = (size_t)K * 2;
    size_t rowSkip = (size_t)128 * K2;
    int rowL = t >> 2;                                  // 0..127
    int slotSw = (((t & 3) ^ ((t >> 3) & 3)) << 4);     // involution of read swizzle
    const char* aSrc = (const char*)A + (size_t)(bm * 256 + rowL) * K2 + slotSw;
    const char* bSrc = (const char*)Bw + (size_t)(bn * 256 + rowL) * K2 + slotSw;

    f32x16 acc[4][2] = {};
    bf16x8 af0[4], af1[4], bf0[4], bf1[4];

#define STAGE(SRC, UOFF, KT, KH) { \
    const char* _s = (SRC) + (size_t)(KT) * 128 + (KH) * 64; \
    __builtin_amdgcn_global_load_lds(AS1(_s), AS3(&smem[(UOFF) + t * 16]), 16, 0, 0); \
    __builtin_amdgcn_global_load_lds(AS1(_s + rowSkip), AS3(&smem[(UOFF) + 8192 + t * 16]), 16, 0, 0); }

// A frags for M-half MH (rows wrow+MH*64 .. +64): DST[2*mi+kb], mi,kb in {0,1}
#define RDA(DST, BUF, KS, MH) { \
    DST[0] = *(const bf16x8*)&smem[(BUF)*65536 + (KS)*16384 + (MH)*4096 + 0*2048 + aOffK0]; \
    DST[1] = *(const bf16x8*)&smem[(BUF)*65536 + (KS)*16384 + (MH)*4096 + 0*2048 + aOffK1]; \
    DST[2] = *(const bf16x8*)&smem[(BUF)*65536 + (KS)*16384 + (MH)*4096 + 1*2048 + aOffK0]; \
    DST[3] = *(const bf16x8*)&smem[(BUF)*65536 + (KS)*16384 + (MH)*4096 + 1*2048 + aOffK1]; }

// B frags: DST[2*ni+kb], ni,kb in {0,1}
#define RDB(DST, BUF, KS) { \
    DST[0] = *(const bf16x8*)&smem[(BUF)*65536 + (KS)*16384 + 0*2048 + bOffK0]; \
    DST[1] = *(const bf16x8*)&smem[(BUF)*65536 + (KS)*16384 + 0*2048 + bOffK1]; \
    DST[2] = *(const bf16x8*)&smem[(BUF)*65536 + (KS)*16384 + 1*2048 + bOffK0]; \
    DST[3] = *(const bf16x8*)&smem[(BUF)*65536 + (KS)*16384 + 1*2048 + bOffK1]; }

// 8x mfma_32x32x16: 2 mi x 2 ni x 2 kb (kb chained on same acc)
#define MFMAQ(AF, BF, MH) { \
    __builtin_amdgcn_s_setprio(1); \
    _Pragma("unroll") \
    for (int mi = 0; mi < 2; ++mi) { \
      _Pragma("unroll") \
      for (int ni = 0; ni < 2; ++ni) { \
        acc[(MH)*2+mi][ni] = __builtin_amdgcn_mfma_f32_32x32x16_bf16(AF[2*mi+0], BF[2*ni+0], acc[(MH)*2+mi][ni], 0, 0, 0); \
        acc[(MH)*2+mi][ni] = __builtin_amdgcn_mfma_f32_32x32x16_bf16(AF[2*mi+1], BF[2*ni+1], acc[(MH)*2+mi][ni], 0, 0, 0); \
      } \
    } \
    __builtin_amdgcn_s_setprio(0); }

#define BAR __builtin_amdgcn_s_barrier()
#define VMC(N) asm volatile("s_waitcnt vmcnt(" #N ")" ::: "memory")

    // ---- prologue: stage T0 (4 units) + T1.k0 (2 units) = 12 loads ----
    STAGE(aSrc, 0,      0, 0);
    STAGE(aSrc, 16384,  0, 1);
    STAGE(bSrc, 32768,  0, 0);
    STAGE(bSrc, 49152,  0, 1);
    STAGE(aSrc, 65536,  1, 0);
    STAGE(bSrc, 98304,  1, 0);
    VMC(6);
    BAR;
    RDA(af0, 0, 0, 0); RDB(bf0, 0, 0);

    const int NIT = K / 128;     // 14 iterations, 2 K-tiles each
    #pragma unroll 1
    for (int it = 0; it < NIT - 1; ++it) {
        int kt1 = 2 * it + 1, kt2 = 2 * it + 2, kt3 = 2 * it + 3;
        MFMAQ(af0, bf0, 0); RDA(af1, 0, 0, 1);
        VMC(4); BAR;
        MFMAQ(af1, bf0, 1); RDA(af0, 0, 1, 0); RDB(bf1, 0, 1);
        STAGE(aSrc, 81920, kt1, 1); STAGE(bSrc, 114688, kt1, 1);
        MFMAQ(af0, bf1, 0); RDA(af1, 0, 1, 1);
        VMC(4); BAR;
        MFMAQ(af1, bf1, 1); RDA(af0, 1, 0, 0); RDB(bf0, 1, 0);
        STAGE(aSrc, 0, kt2, 0); STAGE(bSrc, 32768, kt2, 0);
        MFMAQ(af0, bf0, 0); RDA(af1, 1, 0, 1);
        VMC(4); BAR;
        MFMAQ(af1, bf0, 1); RDA(af0, 1, 1, 0); RDB(bf1, 1, 1);
        STAGE(aSrc, 16384, kt2, 1); STAGE(bSrc, 49152, kt2, 1);
        MFMAQ(af0, bf1, 0); RDA(af1, 1, 1, 1);
        VMC(4); BAR;
        MFMAQ(af1, bf1, 1); RDA(af0, 0, 0, 0); RDB(bf0, 0, 0);
        STAGE(aSrc, 65536, kt3, 0); STAGE(bSrc, 98304, kt3, 0);
    }
    // ---- peeled final iteration ----
    {
        int kt1 = 2 * NIT - 1;
        MFMAQ(af0, bf0, 0); RDA(af1, 0, 0, 1);
        VMC(4); BAR;
        MFMAQ(af1, bf0, 1); RDA(af0, 0, 1, 0); RDB(bf1, 0, 1);
        STAGE(aSrc, 81920, kt1, 1); STAGE(bSrc, 114688, kt1, 1);
        MFMAQ(af0, bf1, 0); RDA(af1, 0, 1, 1);
        VMC(4); BAR;
        MFMAQ(af1, bf1, 1); RDA(af0, 1, 0, 0); RDB(bf0, 1, 0);
        MFMAQ(af0, bf0, 0); RDA(af1, 1, 0, 1);
        VMC(0); BAR;
        MFMAQ(af1, bf0, 1); RDA(af0, 1, 1, 0); RDB(bf1, 1, 1);
        MFMAQ(af0, bf1, 0); RDA(af1, 1, 1, 1);
        BAR;
        MFMAQ(af1, bf1, 1);
    }

#undef STAGE
#undef RDA
#undef RDB
#undef MFMAQ
#undef BAR
#undef VMC

    // ---- epilogue: C/D 32x32: col = lane&31, row = (reg&3)+8*(reg>>2)+4*hi ----
    float*  Cf = (float*)Cout;
    ushort* Cb = (ushort*)Cout;
    #pragma unroll
    for (int mi = 0; mi < 4; ++mi) {
        int rbase = bm * 256 + wrow + mi * 32 + 4 * hi;
        #pragma unroll
        for (int ni = 0; ni < 2; ++ni) {
            int col = bn * 256 + wcol + ni * 32 + l5;
            float bv = bias[col];
            #pragma unroll
            for (int reg = 0; reg < 16; ++reg) {
                int row = rbase + (reg & 3) + 8 * (reg >> 2);
                float val = acc[mi][ni][reg] + bv;
                size_t off = (size_t)row * N + col;
                if (OUT_BF16) Cb[off] = f2bf(val);
                else          Cf[off] = val;
            }
        }
    }
}

// ---------------- 5x5 masked attention, 2 (b,h) pairs per wave ----------------
__global__ __launch_bounds__(256) void attn_kernel(
    const ushort* __restrict__ qkv,
    const int* __restrict__ adj,
    ushort* __restrict__ outp)
{
    int gw = blockIdx.x * 8 + (threadIdx.x >> 5);  // (b,h) pair index
    int l2 = threadIdx.x & 31;
    int b = gw / Hn;
    int h = gw - b * Hn;

    const ushort* base = qkv + (size_t)b * 5 * N1 + h * HDm + 4 * l2;
    float q[5][4], k[5][4], v[5][4];
    #pragma unroll
    for (int i = 0; i < 5; ++i) {
        ushort4 qq = *reinterpret_cast<const ushort4*>(base + (size_t)i * N1);
        ushort4 kk = *reinterpret_cast<const ushort4*>(base + (size_t)i * N1 + Dm);
        ushort4 vv = *reinterpret_cast<const ushort4*>(base + (size_t)i * N1 + 2 * Dm);
        q[i][0] = bf2f(qq.x); q[i][1] = bf2f(qq.y); q[i][2] = bf2f(qq.z); q[i][3] = bf2f(qq.w);
        k[i][0] = bf2f(kk.x); k[i][1] = bf2f(kk.y); k[i][2] = bf2f(kk.z); k[i][3] = bf2f(kk.w);
        v[i][0] = bf2f(vv.x); v[i][1] = bf2f(vv.y); v[i][2] = bf2f(vv.z); v[i][3] = bf2f(vv.w);
    }

    float s[5][5];
    #pragma unroll
    for (int i = 0; i < 5; ++i)
        #pragma unroll
        for (int j = 0; j < 5; ++j) {
            float p = q[i][0] * k[j][0] + q[i][1] * k[j][1]
                    + q[i][2] * k[j][2] + q[i][3] * k[j][3];
            #pragma unroll
            for (int off = 16; off > 0; off >>= 1)
                p += __shfl_xor(p, off);
            s[i][j] = p;
        }

    const float scale = 0.08838834764831845f;  // 1/sqrt(128)
    float aw[5][5];
    #pragma unroll
    for (int i = 0; i < 5; ++i) {
        float sv[5];
        float mx = -3.0e38f;
        #pragma unroll
        for (int j = 0; j < 5; ++j) {
            float val = s[i][j] * scale + (adj[i * 5 + j] == 0 ? -1e30f : 0.0f);
            sv[j] = val;
            mx = fmaxf(mx, val);
        }
        float denom = 0.0f;
        #pragma unroll
        for (int j = 0; j < 5; ++j) { sv[j] = __expf(sv[j] - mx); denom += sv[j]; }
        float rd = 1.0f / denom;
        #pragma unroll
        for (int j = 0; j < 5; ++j) aw[i][j] = sv[j] * rd;
    }

    ushort* ob = outp + (size_t)b * 5 * Dm + h * HDm + 4 * l2;
    #pragma unroll
    for (int i = 0; i < 5; ++i) {
        float o0 = 0.0f, o1 = 0.0f, o2 = 0.0f, o3 = 0.0f;
        #pragma unroll
        for (int j = 0; j < 5; ++j) {
            o0 += aw[i][j] * v[j][0]; o1 += aw[i][j] * v[j][1];
            o2 += aw[i][j] * v[j][2]; o3 += aw[i][j] * v[j][3];
        }
        ushort4 ov;
        ov.x = f2bf(o0); ov.y = f2bf(o1); ov.z = f2bf(o2); ov.w = f2bf(o3);
        *reinterpret_cast<ushort4*>(ob + (size_t)i * Dm) = ov;
    }
}

extern "C" void kernel_launch(void* const* d_in, const int* in_sizes, int n_in,
                              void* d_out, int out_size, void* d_ws, size_t ws_size,
                              hipStream_t stream) {
    const float* vertices  = (const float*)d_in[0];
    const int*   adjacency = (const int*)  d_in[1];
    const float* w1        = (const float*)d_in[2];
    const float* b1        = (const float*)d_in[3];
    const float* w2        = (const float*)d_in[4];
    const float* b2        = (const float*)d_in[5];
    float* out = (float*)d_out;

    char* ws = (char*)d_ws;
    const size_t vertBytes = (size_t)Mrows * Kd * 2;
    const size_t qkvBytes  = (size_t)Mrows * N1 * 2;
    const size_t w1Bytes   = (size_t)N1 * Kd * 2;
    const size_t w2Bytes   = (size_t)Dm * Dm * 2;
    const size_t needed    = vertBytes + qkvBytes + w1Bytes + w2Bytes;
    if (ws_size < needed) return;

    ushort* vert_bf = (ushort*)ws;
    ushort* qkv_bf  = (ushort*)(ws + vertBytes);
    ushort* w1_bf   = (ushort*)(ws + vertBytes + qkvBytes);
    ushort* w2_bf   = (ushort*)(ws + vertBytes + qkvBytes + w1Bytes);

    // single fused conversion launch (3 regions)
    cvt3_kernel<<<2048, 256, 0, stream>>>(
        vertices, vert_bf, Mrows * Kd / 4,
        w1, w1_bf, N1 * Kd / 4,
        w2, w2_bf, Dm * Dm / 4);

    // GEMM1: qkv = vertices @ W1^T + b1   (bf16 out). grid 160*21=3360 (%8==0)
    gemm8p<true><<<(Mrows / 256) * (N1 / 256), 512, 0, stream>>>(
        vert_bf, w1_bf, b1, qkv_bf, Mrows, N1, Kd);

    // attention: 2 pairs/wave, 8 pairs/block -> 14336 blocks
    attn_kernel<<<Bsz * Hn / 8, 256, 0, stream>>>(qkv_bf, adjacency, vert_bf);

    // GEMM2: out = attn_out @ W2^T + b2   (f32 out). grid 160*7=1120 (%8==0)
    gemm8p<false><<<(Mrows / 256) * (Dm / 256), 512, 0, stream>>>(
        vert_bf, w2_bf, b2, out, Mrows, Dm, Kd);
}

// Round 14
// 1113.847 us; speedup vs baseline: 1.1211x; 1.1211x over previous
//
#include <hip/hip_runtime.h>
#include <hip/hip_bf16.h>

// Problem constants (PentachoronCrossAttention)
#define Bsz   8192
#define Vn    5
#define Dm    1792
#define Hn    14
#define HDm   128
#define Mrows (Bsz * Vn)   // 40960
#define N1    (3 * Dm)     // 5376
#define Kd    Dm           // 1792

typedef float f32x4 __attribute__((ext_vector_type(4)));
typedef short bf16x8 __attribute__((ext_vector_type(8)));

__device__ __forceinline__ ushort f2bf(float f) {
    unsigned u = __float_as_uint(f);
    u += 0x7fffu + ((u >> 16) & 1u);   // round-to-nearest-even
    return (ushort)(u >> 16);
}
__device__ __forceinline__ float bf2f(ushort h) {
    return __uint_as_float(((unsigned)h) << 16);
}

#define AS1(p) ((const __attribute__((address_space(1))) void*)(p))
#define AS3(p) ((__attribute__((address_space(3))) void*)(p))

// ---------------- fused f32 -> bf16 convert (3 regions, one launch) ----------------
__global__ void cvt3_kernel(const float* __restrict__ in0, ushort* __restrict__ out0, int n0,
                            const float* __restrict__ in1, ushort* __restrict__ out1, int n1,
                            const float* __restrict__ in2, ushort* __restrict__ out2, int n2) {
    int i = blockIdx.x * blockDim.x + threadIdx.x;
    int stride = gridDim.x * blockDim.x;
    int ntot = n0 + n1 + n2;
    for (int idx = i; idx < ntot; idx += stride) {
        const float* src; ushort* dst; int k;
        if (idx < n0)            { src = in0; dst = out0; k = idx; }
        else if (idx < n0 + n1)  { src = in1; dst = out1; k = idx - n0; }
        else                     { src = in2; dst = out2; k = idx - n0 - n1; }
        float4 v = reinterpret_cast<const float4*>(src)[k];
        ushort4 o;
        o.x = f2bf(v.x); o.y = f2bf(v.y); o.z = f2bf(v.z); o.w = f2bf(v.w);
        reinterpret_cast<ushort4*>(dst)[k] = o;
    }
}

// ---------------- 256x256 8-phase bf16 GEMM, C = A * Bw^T + bias ----------------
// FROZEN at round-12 (best verified: GEMM1 677us, MfmaUtil 60%, bank-conflicts 0,
// total 1113us). 16x16x32 MFMA — do NOT switch to 32x32x16: r13 measured 7.2e7
// bank conflicts under this LDS layout (HW lane-grouping differs from the
// per-8-lane quad model; the 16x16 4-slot-group x 16-row pattern is clean).
// LDS (128 KiB): buf b at b*65536; A k-half kh at +kh*16384; B at +32768+kh*16384.
// Unit = [256 rows][4 slots of 16B], swizzle phys_slot = log_slot ^ ((row>>1)&3).
// 2-phase windows: stages batched on EVEN phases; barrier + VMC(4) at ODD ends.
// WAR: stage at even p overwrites unit consumed at p-1 (odd). vmcnt ledger:
// VMC(4) uniform steady; prologue VMC(6); peel 4/4/0. Grouped raster (G=4).
template<bool OUT_BF16>
__global__ __launch_bounds__(512, 2) void gemm8p(
    const ushort* __restrict__ A,
    const ushort* __restrict__ Bw,
    const float* __restrict__ bias,
    void* __restrict__ Cout,
    int M, int N, int K)
{
    __shared__ __align__(16) char smem[131072];

    const int nTN = N >> 8;
    int bid = blockIdx.x;
    int cpx = gridDim.x >> 3;                 // grid % 8 == 0 for both launches
    int swz = (bid & 7) * cpx + (bid >> 3);   // XCD-bijective chunk swizzle
    int gsz = 4 * nTN;
    int g = swz / gsz, r = swz - g * gsz;
    int bm = g * 4 + (r & 3);
    int bn = r >> 2;

    int t = threadIdx.x;
    int lane = t & 63, w = t >> 6;
    int wrow = (w >> 2) * 128;                // 2 waves in M
    int wcol = (w & 3) * 64;                  // 4 waves in N
    int fr = lane & 15, fq = lane >> 4;
    int slotC = ((fq ^ ((fr >> 1) & 3)) << 4);   // swizzled 16B slot (lane-const)
    int aOff = (wrow + fr) * 64 + slotC;
    int bOff = 32768 + (wcol + fr) * 64 + slotC;

    size_t K2 = (size_t)K * 2;
    size_t rowSkip = (size_t)128 * K2;
    int rowL = t >> 2;                                  // 0..127
    int slotSw = (((t & 3) ^ ((t >> 3) & 3)) << 4);     // involution of read swizzle
    const char* aSrc = (const char*)A + (size_t)(bm * 256 + rowL) * K2 + slotSw;
    const char* bSrc = (const char*)Bw + (size_t)(bn * 256 + rowL) * K2 + slotSw;

    f32x4 acc[8][4] = {};
    bf16x8 af0[4], af1[4], bf0[4], bf1[4];

#define STAGE(SRC, UOFF, KT, KH) { \
    const char* _s = (SRC) + (size_t)(KT) * 128 + (KH) * 64; \
    __builtin_amdgcn_global_load_lds(AS1(_s), AS3(&smem[(UOFF) + t * 16]), 16, 0, 0); \
    __builtin_amdgcn_global_load_lds(AS1(_s + rowSkip), AS3(&smem[(UOFF) + 8192 + t * 16]), 16, 0, 0); }

#define RDA(DST, BUF, KS, M0) { \
    DST[0] = *(const bf16x8*)&smem[(BUF)*65536 + (KS)*16384 + ((M0)+0)*1024 + aOff]; \
    DST[1] = *(const bf16x8*)&smem[(BUF)*65536 + (KS)*16384 + ((M0)+1)*1024 + aOff]; \
    DST[2] = *(const bf16x8*)&smem[(BUF)*65536 + (KS)*16384 + ((M0)+2)*1024 + aOff]; \
    DST[3] = *(const bf16x8*)&smem[(BUF)*65536 + (KS)*16384 + ((M0)+3)*1024 + aOff]; }

#define RDB(DST, BUF, KS) { \
    DST[0] = *(const bf16x8*)&smem[(BUF)*65536 + (KS)*16384 + 0*1024 + bOff]; \
    DST[1] = *(const bf16x8*)&smem[(BUF)*65536 + (KS)*16384 + 1*1024 + bOff]; \
    DST[2] = *(const bf16x8*)&smem[(BUF)*65536 + (KS)*16384 + 2*1024 + bOff]; \
    DST[3] = *(const bf16x8*)&smem[(BUF)*65536 + (KS)*16384 + 3*1024 + bOff]; }

#define MFMAQ(AF, BF, M0) { \
    __builtin_amdgcn_s_setprio(1); \
    _Pragma("unroll") \
    for (int mi = 0; mi < 4; ++mi) { \
      _Pragma("unroll") \
      for (int ni = 0; ni < 4; ++ni) \
        acc[(M0)+mi][ni] = __builtin_amdgcn_mfma_f32_16x16x32_bf16(AF[mi], BF[ni], acc[(M0)+mi][ni], 0, 0, 0); \
    } \
    __builtin_amdgcn_s_setprio(0); }

#define BAR __builtin_amdgcn_s_barrier()
#define VMC(N) asm volatile("s_waitcnt vmcnt(" #N ")" ::: "memory")

    // ---- prologue: stage T0 (4 units) + T1.k0 (2 units) = 12 loads ----
    STAGE(aSrc, 0,      0, 0);
    STAGE(aSrc, 16384,  0, 1);
    STAGE(bSrc, 32768,  0, 0);
    STAGE(bSrc, 49152,  0, 1);
    STAGE(aSrc, 65536,  1, 0);
    STAGE(bSrc, 98304,  1, 0);
    VMC(6);
    BAR;
    RDA(af0, 0, 0, 0); RDB(bf0, 0, 0);

    const int NIT = K / 128;     // 14 iterations, 2 K-tiles each
    #pragma unroll 1
    for (int it = 0; it < NIT - 1; ++it) {
        int kt1 = 2 * it + 1, kt2 = 2 * it + 2, kt3 = 2 * it + 3;
        MFMAQ(af0, bf0, 0); RDA(af1, 0, 0, 4);
        VMC(4); BAR;
        MFMAQ(af1, bf0, 4); RDA(af0, 0, 1, 0); RDB(bf1, 0, 1);
        STAGE(aSrc, 81920, kt1, 1); STAGE(bSrc, 114688, kt1, 1);
        MFMAQ(af0, bf1, 0); RDA(af1, 0, 1, 4);
        VMC(4); BAR;
        MFMAQ(af1, bf1, 4); RDA(af0, 1, 0, 0); RDB(bf0, 1, 0);
        STAGE(aSrc, 0, kt2, 0); STAGE(bSrc, 32768, kt2, 0);
        MFMAQ(af0, bf0, 0); RDA(af1, 1, 0, 4);
        VMC(4); BAR;
        MFMAQ(af1, bf0, 4); RDA(af0, 1, 1, 0); RDB(bf1, 1, 1);
        STAGE(aSrc, 16384, kt2, 1); STAGE(bSrc, 49152, kt2, 1);
        MFMAQ(af0, bf1, 0); RDA(af1, 1, 1, 4);
        VMC(4); BAR;
        MFMAQ(af1, bf1, 4); RDA(af0, 0, 0, 0); RDB(bf0, 0, 0);
        STAGE(aSrc, 65536, kt3, 0); STAGE(bSrc, 98304, kt3, 0);
    }
    // ---- peeled final iteration ----
    {
        int kt1 = 2 * NIT - 1;
        MFMAQ(af0, bf0, 0); RDA(af1, 0, 0, 4);
        VMC(4); BAR;
        MFMAQ(af1, bf0, 4); RDA(af0, 0, 1, 0); RDB(bf1, 0, 1);
        STAGE(aSrc, 81920, kt1, 1); STAGE(bSrc, 114688, kt1, 1);
        MFMAQ(af0, bf1, 0); RDA(af1, 0, 1, 4);
        VMC(4); BAR;
        MFMAQ(af1, bf1, 4); RDA(af0, 1, 0, 0); RDB(bf0, 1, 0);
        MFMAQ(af0, bf0, 0); RDA(af1, 1, 0, 4);
        VMC(0); BAR;
        MFMAQ(af1, bf0, 4); RDA(af0, 1, 1, 0); RDB(bf1, 1, 1);
        MFMAQ(af0, bf1, 0); RDA(af1, 1, 1, 4);
        BAR;
        MFMAQ(af1, bf1, 4);
    }

#undef STAGE
#undef RDA
#undef RDB
#undef MFMAQ
#undef BAR
#undef VMC

    // ---- epilogue: C/D layout col=lane&15, row=(lane>>4)*4+reg ----
    float*  Cf = (float*)Cout;
    ushort* Cb = (ushort*)Cout;
    #pragma unroll
    for (int mi = 0; mi < 8; ++mi) {
        int row0 = bm * 256 + wrow + mi * 16 + fq * 4;
        #pragma unroll
        for (int ni = 0; ni < 4; ++ni) {
            int col = bn * 256 + wcol + ni * 16 + fr;
            float bv = bias[col];
            #pragma unroll
            for (int rr = 0; rr < 4; ++rr) {
                float val = acc[mi][ni][rr] + bv;
                size_t off = (size_t)(row0 + rr) * N + col;
                if (OUT_BF16) Cb[off] = f2bf(val);
                else          Cf[off] = val;
            }
        }
    }
}

// ---------------- 5x5 masked attention, 2 (b,h) pairs per wave ----------------
// 8B/lane vectorization. Lanes 0-31 = pair0, lanes 32-63 = pair1.
// Lane (l&31) owns head dims 4*(l&31)..+3 (ushort4). Per 32-lane group:
// loads/stores are 32x8B = 256B contiguous; dot reduce via shfl_xor 16..1.
__global__ __launch_bounds__(256) void attn_kernel(
    const ushort* __restrict__ qkv,
    const int* __restrict__ adj,
    ushort* __restrict__ outp)
{
    int gw = blockIdx.x * 8 + (threadIdx.x >> 5);  // (b,h) pair index
    int l2 = threadIdx.x & 31;
    int b = gw / Hn;
    int h = gw - b * Hn;

    const ushort* base = qkv + (size_t)b * 5 * N1 + h * HDm + 4 * l2;
    float q[5][4], k[5][4], v[5][4];
    #pragma unroll
    for (int i = 0; i < 5; ++i) {
        ushort4 qq = *reinterpret_cast<const ushort4*>(base + (size_t)i * N1);
        ushort4 kk = *reinterpret_cast<const ushort4*>(base + (size_t)i * N1 + Dm);
        ushort4 vv = *reinterpret_cast<const ushort4*>(base + (size_t)i * N1 + 2 * Dm);
        q[i][0] = bf2f(qq.x); q[i][1] = bf2f(qq.y); q[i][2] = bf2f(qq.z); q[i][3] = bf2f(qq.w);
        k[i][0] = bf2f(kk.x); k[i][1] = bf2f(kk.y); k[i][2] = bf2f(kk.z); k[i][3] = bf2f(kk.w);
        v[i][0] = bf2f(vv.x); v[i][1] = bf2f(vv.y); v[i][2] = bf2f(vv.z); v[i][3] = bf2f(vv.w);
    }

    float s[5][5];
    #pragma unroll
    for (int i = 0; i < 5; ++i)
        #pragma unroll
        for (int j = 0; j < 5; ++j) {
            float p = q[i][0] * k[j][0] + q[i][1] * k[j][1]
                    + q[i][2] * k[j][2] + q[i][3] * k[j][3];
            #pragma unroll
            for (int off = 16; off > 0; off >>= 1)
                p += __shfl_xor(p, off);
            s[i][j] = p;
        }

    const float scale = 0.08838834764831845f;  // 1/sqrt(128)
    float aw[5][5];
    #pragma unroll
    for (int i = 0; i < 5; ++i) {
        float sv[5];
        float mx = -3.0e38f;
        #pragma unroll
        for (int j = 0; j < 5; ++j) {
            float val = s[i][j] * scale + (adj[i * 5 + j] == 0 ? -1e30f : 0.0f);
            sv[j] = val;
            mx = fmaxf(mx, val);
        }
        float denom = 0.0f;
        #pragma unroll
        for (int j = 0; j < 5; ++j) { sv[j] = __expf(sv[j] - mx); denom += sv[j]; }
        float rd = 1.0f / denom;
        #pragma unroll
        for (int j = 0; j < 5; ++j) aw[i][j] = sv[j] * rd;
    }

    ushort* ob = outp + (size_t)b * 5 * Dm + h * HDm + 4 * l2;
    #pragma unroll
    for (int i = 0; i < 5; ++i) {
        float o0 = 0.0f, o1 = 0.0f, o2 = 0.0f, o3 = 0.0f;
        #pragma unroll
        for (int j = 0; j < 5; ++j) {
            o0 += aw[i][j] * v[j][0]; o1 += aw[i][j] * v[j][1];
            o2 += aw[i][j] * v[j][2]; o3 += aw[i][j] * v[j][3];
        }
        ushort4 ov;
        ov.x = f2bf(o0); ov.y = f2bf(o1); ov.z = f2bf(o2); ov.w = f2bf(o3);
        *reinterpret_cast<ushort4*>(ob + (size_t)i * Dm) = ov;
    }
}

extern "C" void kernel_launch(void* const* d_in, const int* in_sizes, int n_in,
                              void* d_out, int out_size, void* d_ws, size_t ws_size,
                              hipStream_t stream) {
    const float* vertices  = (const float*)d_in[0];
    const int*   adjacency = (const int*)  d_in[1];
    const float* w1        = (const float*)d_in[2];
    const float* b1        = (const float*)d_in[3];
    const float* w2        = (const float*)d_in[4];
    const float* b2        = (const float*)d_in[5];
    float* out = (float*)d_out;

    char* ws = (char*)d_ws;
    const size_t vertBytes = (size_t)Mrows * Kd * 2;
    const size_t qkvBytes  = (size_t)Mrows * N1 * 2;
    const size_t w1Bytes   = (size_t)N1 * Kd * 2;
    const size_t w2Bytes   = (size_t)Dm * Dm * 2;
    const size_t needed    = vertBytes + qkvBytes + w1Bytes + w2Bytes;
    if (ws_size < needed) return;

    ushort* vert_bf = (ushort*)ws;
    ushort* qkv_bf  = (ushort*)(ws + vertBytes);
    ushort* w1_bf   = (ushort*)(ws + vertBytes + qkvBytes);
    ushort* w2_bf   = (ushort*)(ws + vertBytes + qkvBytes + w1Bytes);

    // single fused conversion launch (3 regions)
    cvt3_kernel<<<2048, 256, 0, stream>>>(
        vertices, vert_bf, Mrows * Kd / 4,
        w1, w1_bf, N1 * Kd / 4,
        w2, w2_bf, Dm * Dm / 4);

    // GEMM1: qkv = vertices @ W1^T + b1   (bf16 out). grid 160*21=3360 (%8==0)
    gemm8p<true><<<(Mrows / 256) * (N1 / 256), 512, 0, stream>>>(
        vert_bf, w1_bf, b1, qkv_bf, Mrows, N1, Kd);

    // attention: 2 pairs/wave, 8 pairs/block -> 14336 blocks
    attn_kernel<<<Bsz * Hn / 8, 256, 0, stream>>>(qkv_bf, adjacency, vert_bf);

    // GEMM2: out = attn_out @ W2^T + b2   (f32 out). grid 160*7=1120 (%8==0)
    gemm8p<false><<<(Mrows / 256) * (Dm / 256), 512, 0, stream>>>(
        vert_bf, w2_bf, b2, out, Mrows, Dm, Kd);
}